// Round 3
// baseline (1193.043 us; speedup 1.0000x reference)
//
#include <hip/hip_runtime.h>

// WindowAttention fused kernel for MI355X (gfx950) — round 3
// B_=8192 windows, N=49 tokens, C=192, H=6 heads, dh=32, NW=64 masks.
// One block = one window, 1024 threads (16 waves), 72KB LDS -> 2 blocks/CU.
// Q and P stay in registers (cross-lane shfl reshuffle); K,V,X/O in LDS.

#define NTOK 49
#define CCH 192

typedef __bf16 bf16_t;
typedef bf16_t bf16x8 __attribute__((ext_vector_type(8)));
typedef bf16_t bf16x4 __attribute__((ext_vector_type(4)));
typedef bf16_t bf16x2 __attribute__((ext_vector_type(2)));
typedef float f32x4 __attribute__((ext_vector_type(4)));

// ws byte offsets
#define WS_WQT   0         // 192*192 bf16, pre-scaled by dh^-0.5 * log2e
#define WS_WKVT  73728     // 384*192 bf16
#define WS_WPT   221184    // 192*192 bf16
#define WS_BQS   294912    // 192 f32 pre-scaled q-bias
#define WS_TBL   295680    // bias/mask tables (mode-dependent, log2e-scaled)

#define SWZ(row, off) ((off) ^ (((row) & 7) << 4))

__device__ __forceinline__ unsigned pk2(float a, float b) {
    bf16x2 w = { (bf16_t)a, (bf16_t)b };
    return __builtin_bit_cast(unsigned, w);
}

__global__ void prep_kernel(const float* __restrict__ Wq, const float* __restrict__ bq,
                            const float* __restrict__ Wkv, const float* __restrict__ Wproj,
                            const float* __restrict__ btab, const int* __restrict__ rel,
                            const float* __restrict__ mask,
                            bf16_t* __restrict__ wqt, bf16_t* __restrict__ wkvt,
                            bf16_t* __restrict__ wpt, float* __restrict__ bqs,
                            float* __restrict__ tbl, int mode) {
    const float SC  = 0.2550718212080052f;   // dh^-0.5 * log2e
    const float L2E = 1.4426950408889634f;
    long i = (long)blockIdx.x * 256 + threadIdx.x;
    if (i < 36864) { int n = i / 192, k = i % 192; wqt[i] = (bf16_t)(Wq[k * 192 + n] * SC); return; }
    i -= 36864;
    if (i < 73728) { int n = i / 192, k = i % 192; wkvt[i] = (bf16_t)Wkv[k * 384 + n]; return; }
    i -= 73728;
    if (i < 36864) { int n = i / 192, k = i % 192; wpt[i] = (bf16_t)Wproj[k * 192 + n]; return; }
    i -= 36864;
    if (i < 192) { bqs[i] = bq[i] * SC; return; }
    i -= 192;
    if (mode == 0) {            // presummed [64][6][49][64], log2e-scaled, pad=-1e30
        if (i < 1204224) {
            int c = i & 63; long r = i >> 6; int q = r % 49; r /= 49; int h = r % 6; int w = r / 6;
            tbl[i] = (c < 49) ? (btab[rel[q * 49 + c] * 6 + h] + mask[(size_t)w * 2401 + q * 49 + c]) * L2E
                              : -1e30f;
        }
    } else if (mode == 1) {     // bias [6][49][64] (pad 0) + mask [64][49][64] (pad -1e30)
        if (i < 18816) { int c = i & 63; int r = i >> 6; int q = r % 49; int h = r / 49;
            tbl[i] = (c < 49) ? btab[rel[q * 49 + c] * 6 + h] * L2E : 0.f; return; }
        i -= 18816;
        if (i < 200704) { int c = i & 63; long r = i >> 6; int q = r % 49; int w = r / 49;
            tbl[18816 + i] = (c < 49) ? mask[(size_t)w * 2401 + q * 49 + c] * L2E : -1e30f; }
    } else {                    // raw gathered bias [6][49][49]
        if (i < 14406) { int h = i / 2401, rc = i % 2401; tbl[i] = btab[rel[rc] * 6 + h]; }
    }
}

__global__ __launch_bounds__(1024, 8) void wattn_kernel(
    const float* __restrict__ xq, const float* __restrict__ mask,
    const float* __restrict__ bkv, const float* __restrict__ bproj,
    const bf16_t* __restrict__ wqt, const bf16_t* __restrict__ wkvt, const bf16_t* __restrict__ wpt,
    const float* __restrict__ bqs, const float* __restrict__ tbl,
    float* __restrict__ out, int mode)
{
    __shared__ __align__(16) unsigned char smem[73728];
    unsigned char* XsO = smem;           // [64][384B] X bf16; O overwrites after phase 2
    unsigned char* Ks  = smem + 24576;   // [64][384B] K[token][chan]
    unsigned char* Vt  = smem + 49152;   // [192][128B] V^T[chan][token]

    const int tid = threadIdx.x;
    const int wid = tid >> 6;
    const int lane = tid & 63;
    const int l15 = lane & 15;
    const int lg = lane >> 4;            // 0..3
    const int b = blockIdx.x;
    const float* xp = xq + (size_t)b * (NTOK * CCH);
    const float LOG2E = 1.4426950408889634f;

    // ---- Phase 1: stage X -> bf16 LDS (rows 49..63 zeroed) ----
    for (int idx = tid; idx < 2352; idx += 1024) {   // 49 rows * 48 float4
        int row = idx / 48;
        int c4 = idx % 48;
        float4 v = *(const float4*)(xp + row * 192 + c4 * 4);
        bf16x4 pk = { (bf16_t)v.x, (bf16_t)v.y, (bf16_t)v.z, (bf16_t)v.w };
        *(bf16x4*)(XsO + row * 384 + SWZ(row, c4 * 8)) = pk;
    }
    if (tid < 720) *(unsigned long long*)(XsO + 49 * 384 + tid * 8) = 0ULL;
    __syncthreads();

    // ---- Phase 2: QKV projection ----
    // Q: wave w computes Q for attention unit a=w (and a=w+16 if w<8); kept in regs.
    const int qt = wid & 3;              // q-tile for both of this wave's attn units
    unsigned qw0[4], qw1[4];
    {
        int xrow = qt * 16 + l15;
        bf16x8 xf[6];
#pragma unroll
        for (int ks = 0; ks < 6; ks++)
            xf[ks] = *(const bf16x8*)(XsO + xrow * 384 + SWZ(xrow, ks * 64 + lg * 16));

        auto qproj = [&](int h, unsigned* qwv) {
#pragma unroll
            for (int dlt = 0; dlt < 2; dlt++) {
                int ut = 2 * h + dlt;
                float4 b4 = *(const float4*)(bqs + ut * 16 + lg * 4);
                f32x4 acc = { b4.x, b4.y, b4.z, b4.w };
                const bf16_t* wr = wqt + (size_t)(ut * 16 + l15) * 192 + lg * 8;
#pragma unroll
                for (int ks = 0; ks < 6; ks++) {
                    bf16x8 bfr = *(const bf16x8*)(wr + ks * 32);
                    acc = __builtin_amdgcn_mfma_f32_16x16x32_bf16(bfr, xf[ks], acc, 0, 0, 0);
                }
                qwv[dlt * 2 + 0] = pk2(acc[0], acc[1]);
                qwv[dlt * 2 + 1] = pk2(acc[2], acc[3]);
            }
        };
        qproj(wid >> 2, qw0);
        if (wid < 8) qproj(4 + (wid >> 2), qw1);
    }
    // K and V: 3 (nt,mt) units per wave, sharing the X fragments.
    for (int i = 0; i < 3; i++) {
        int u = 3 * wid + i;
        int nt = u >> 2, mt = u & 3;
        int xr = mt * 16 + l15;
        bf16x8 xfk[6];
#pragma unroll
        for (int ks = 0; ks < 6; ks++)
            xfk[ks] = *(const bf16x8*)(XsO + xr * 384 + SWZ(xr, ks * 64 + lg * 16));
        // K (swapped): D[outchan][token]
        float4 kb4 = *(const float4*)(bkv + nt * 16 + lg * 4);
        f32x4 ka = { kb4.x, kb4.y, kb4.z, kb4.w };
        const bf16_t* wrk = wkvt + (size_t)(nt * 16 + l15) * 192 + lg * 8;
#pragma unroll
        for (int ks = 0; ks < 6; ks++) {
            bf16x8 bfr = *(const bf16x8*)(wrk + ks * 32);
            ka = __builtin_amdgcn_mfma_f32_16x16x32_bf16(bfr, xfk[ks], ka, 0, 0, 0);
        }
        bf16x4 kp = { (bf16_t)ka[0], (bf16_t)ka[1], (bf16_t)ka[2], (bf16_t)ka[3] };
        *(bf16x4*)(Ks + xr * 384 + SWZ(xr, nt * 32 + lg * 8)) = kp;
        // V (normal): D[token][chan] -> store transposed into Vt[chan][token]
        float bv = bkv[192 + nt * 16 + l15];
        f32x4 va = { bv, bv, bv, bv };
        const bf16_t* wrv = wkvt + (size_t)(192 + nt * 16 + l15) * 192 + lg * 8;
#pragma unroll
        for (int ks = 0; ks < 6; ks++) {
            bf16x8 bfr = *(const bf16x8*)(wrv + ks * 32);
            va = __builtin_amdgcn_mfma_f32_16x16x32_bf16(xfk[ks], bfr, va, 0, 0, 0);
        }
        int vr = nt * 16 + l15;
        bf16x4 vp = { (bf16_t)va[0], (bf16_t)va[1], (bf16_t)va[2], (bf16_t)va[3] };
        *(bf16x4*)(Vt + vr * 128 + SWZ(vr, mt * 32 + lg * 8)) = vp;
    }
    __syncthreads();

    // ---- Phase 3: attention; Q from regs, P via shfl, O -> XsO ----
    const int widx = b & 63;
    auto attn_unit = [&](int h, const unsigned* qwv) {
        // assemble qfr: lane needs Q[chan h*32+lg*8+e][q=qt*16+l15]
        unsigned qword[4];
#pragma unroll
        for (int i = 0; i < 4; i++) {
            int src = l15 + 16 * (((lg & 1) << 1) | (i >> 1));
            unsigned v0 = (unsigned)__shfl((int)qwv[(i & 1)], src, 64);
            unsigned v1 = (unsigned)__shfl((int)qwv[2 + (i & 1)], src, 64);
            qword[i] = (lg & 2) ? v1 : v0;
        }
        uint4 qq = { qword[0], qword[1], qword[2], qword[3] };
        bf16x8 qfr = __builtin_bit_cast(bf16x8, qq);
        // QK^T (S^T orientation: col=q, row=ktok)
        f32x4 s[4];
#pragma unroll
        for (int f = 0; f < 4; f++) {
            int kr = f * 16 + l15;
            bf16x8 kfr = *(const bf16x8*)(Ks + kr * 384 + SWZ(kr, h * 64 + lg * 16));
            f32x4 z = { 0.f, 0.f, 0.f, 0.f };
            s[f] = __builtin_amdgcn_mfma_f32_16x16x32_bf16(kfr, qfr, z, 0, 0, 0);
        }
        int q = qt * 16 + l15;
        bool qok = (q < 49);
        // bias + mask (log2e domain; table pads carry -1e30)
        if (mode == 0) {
#pragma unroll
            for (int f = 0; f < 4; f++) {
                if (qok) {
                    float4 bm = *(const float4*)(tbl + (((size_t)(widx * 6 + h) * 49 + q) << 6) + f * 16 + lg * 4);
                    s[f][0] += bm.x; s[f][1] += bm.y; s[f][2] += bm.z; s[f][3] += bm.w;
                }
            }
        } else if (mode == 1) {
#pragma unroll
            for (int f = 0; f < 4; f++) {
                if (qok) {
                    float4 b1 = *(const float4*)(tbl + (((size_t)(h * 49 + q)) << 6) + f * 16 + lg * 4);
                    float4 m1 = *(const float4*)(tbl + 18816 + (((size_t)(widx * 49 + q)) << 6) + f * 16 + lg * 4);
                    s[f][0] += b1.x + m1.x; s[f][1] += b1.y + m1.y;
                    s[f][2] += b1.z + m1.z; s[f][3] += b1.w + m1.w;
                }
            }
        } else {
#pragma unroll
            for (int f = 0; f < 4; f++)
#pragma unroll
                for (int j = 0; j < 4; j++) {
                    int k = f * 16 + lg * 4 + j;
                    if (k >= 49) s[f][j] = -1e30f;
                    else if (qok)
                        s[f][j] += (tbl[h * 2401 + q * 49 + k] + mask[(size_t)widx * 2401 + q * 49 + k]) * LOG2E;
                }
        }
        // softmax over k (exp2 domain): in-lane 16 + lg-group reduce
        float m = s[0][0];
#pragma unroll
        for (int f = 0; f < 4; f++)
#pragma unroll
            for (int j = 0; j < 4; j++) m = fmaxf(m, s[f][j]);
        m = fmaxf(m, __shfl_xor(m, 16));
        m = fmaxf(m, __shfl_xor(m, 32));
        float t = 0.f;
#pragma unroll
        for (int f = 0; f < 4; f++)
#pragma unroll
            for (int j = 0; j < 4; j++) { s[f][j] = __builtin_amdgcn_exp2f(s[f][j] - m); t += s[f][j]; }
        t += __shfl_xor(t, 16);
        t += __shfl_xor(t, 32);
        float inv = __builtin_amdgcn_rcpf(t);
        // pack P (unnormalized) and reshuffle into PV A... B-operand layout
        unsigned Wp[8];
#pragma unroll
        for (int f = 0; f < 4; f++) {
            Wp[f * 2 + 0] = pk2(s[f][0], s[f][1]);
            Wp[f * 2 + 1] = pk2(s[f][2], s[f][3]);
        }
        bf16x8 pa[2];
#pragma unroll
        for (int ks2 = 0; ks2 < 2; ks2++) {
            unsigned pw[4];
#pragma unroll
            for (int p = 0; p < 4; p++) {
                int src = l15 + 16 * (((lg & 1) << 1) | (p >> 1));
                unsigned v0 = (unsigned)__shfl((int)Wp[(2 * ks2) * 2 + (p & 1)], src, 64);
                unsigned v1 = (unsigned)__shfl((int)Wp[(2 * ks2 + 1) * 2 + (p & 1)], src, 64);
                pw[p] = (lg & 2) ? v1 : v0;
            }
            uint4 pp = { pw[0], pw[1], pw[2], pw[3] };
            pa[ks2] = __builtin_bit_cast(bf16x8, pp);
        }
        // PV (swapped): D[chan][q]; normalize post-hoc with inv (per-lane q=l15)
#pragma unroll
        for (int dt = 0; dt < 2; dt++) {
            f32x4 acc = { 0.f, 0.f, 0.f, 0.f };
#pragma unroll
            for (int ks2 = 0; ks2 < 2; ks2++) {
                int vr = h * 32 + dt * 16 + l15;
                bf16x8 vfr = *(const bf16x8*)(Vt + vr * 128 + SWZ(vr, ks2 * 64 + lg * 16));
                acc = __builtin_amdgcn_mfma_f32_16x16x32_bf16(vfr, pa[ks2], acc, 0, 0, 0);
            }
            int orow = qt * 16 + l15;
            bf16x4 op4 = { (bf16_t)(acc[0] * inv), (bf16_t)(acc[1] * inv),
                           (bf16_t)(acc[2] * inv), (bf16_t)(acc[3] * inv) };
            *(bf16x4*)(XsO + orow * 384 + SWZ(orow, h * 64 + dt * 32 + lg * 8)) = op4;
        }
    };
    attn_unit(wid >> 2, qw0);
    if (wid < 8) attn_unit(4 + (wid >> 2), qw1);
    __syncthreads();

    // ---- Phase 4: out projection (swapped), float4 global stores ----
    {
        float* op = out + (size_t)b * (NTOK * CCH);
        for (int i = 0; i < 3; i++) {
            int u = 3 * wid + i;
            int nt = u >> 2, mt = u & 3;
            float4 b4 = *(const float4*)(bproj + nt * 16 + lg * 4);
            f32x4 acc = { b4.x, b4.y, b4.z, b4.w };
            const bf16_t* wr = wpt + (size_t)(nt * 16 + l15) * 192 + lg * 8;
            int orow = mt * 16 + l15;
#pragma unroll
            for (int ks = 0; ks < 6; ks++) {
                bf16x8 bfr = *(const bf16x8*)(wr + ks * 32);
                bf16x8 of = *(const bf16x8*)(XsO + orow * 384 + SWZ(orow, ks * 64 + lg * 16));
                acc = __builtin_amdgcn_mfma_f32_16x16x32_bf16(bfr, of, acc, 0, 0, 0);
            }
            if (orow < 49) {
                float4 st = { acc[0], acc[1], acc[2], acc[3] };
                *(float4*)(op + orow * 192 + nt * 16 + lg * 4) = st;
            }
        }
    }
}

extern "C" void kernel_launch(void* const* d_in, const int* in_sizes, int n_in,
                              void* d_out, int out_size, void* d_ws, size_t ws_size,
                              hipStream_t stream) {
    const float* xq    = (const float*)d_in[0];
    const float* mask  = (const float*)d_in[1];
    const float* Wq    = (const float*)d_in[2];
    const float* bq    = (const float*)d_in[3];
    const float* Wkv   = (const float*)d_in[4];
    const float* bkv   = (const float*)d_in[5];
    const float* Wproj = (const float*)d_in[6];
    const float* bproj = (const float*)d_in[7];
    const float* btab  = (const float*)d_in[8];
    const int*   rel   = (const int*)d_in[9];
    float* out = (float*)d_out;

    char* ws = (char*)d_ws;
    bf16_t* wqt  = (bf16_t*)(ws + WS_WQT);
    bf16_t* wkvt = (bf16_t*)(ws + WS_WKVT);
    bf16_t* wpt  = (bf16_t*)(ws + WS_WPT);
    float*  bqs  = (float*)(ws + WS_BQS);
    float*  tbl  = (float*)(ws + WS_TBL);

    size_t need0 = (size_t)WS_TBL + 1204224u * 4u;   // presummed padded table
    size_t need1 = (size_t)WS_TBL + 219520u * 4u;    // split padded tables
    int mode = (ws_size >= need0) ? 0 : (ws_size >= need1 ? 1 : 2);

    long tblN = (mode == 0) ? 1204224L : (mode == 1 ? 219520L : 14406L);
    long prep_elems = 147648L + tblN;
    int prep_blocks = (int)((prep_elems + 255) / 256);
    prep_kernel<<<prep_blocks, 256, 0, stream>>>(Wq, bq, Wkv, Wproj, btab, rel, mask,
                                                 wqt, wkvt, wpt, bqs, tbl, mode);
    wattn_kernel<<<8192, 1024, 0, stream>>>(xq, mask, bkv, bproj, wqt, wkvt, wpt,
                                            bqs, tbl, out, mode);
}

// Round 4
// 736.852 us; speedup vs baseline: 1.6191x; 1.6191x over previous
//
#include <hip/hip_runtime.h>

// WindowAttention fused kernel for MI355X (gfx950) — round 4
// B_=8192 windows, N=49 tokens, C=192, H=6 heads, dh=32, NW=64 masks.
// One block = one window, 512 threads (8 waves), 72KB LDS -> 2 blocks/CU.
// X loaded global->regs (no X LDS); P in regs via shfl; Q/O overlay in LDS.

#define NTOK 49
#define CCH 192

typedef __bf16 bf16_t;
typedef bf16_t bf16x8 __attribute__((ext_vector_type(8)));
typedef bf16_t bf16x4 __attribute__((ext_vector_type(4)));
typedef bf16_t bf16x2 __attribute__((ext_vector_type(2)));
typedef float f32x4 __attribute__((ext_vector_type(4)));

// ws byte offsets
#define WS_WQT   0         // 192*192 bf16, pre-scaled by dh^-0.5 * log2e
#define WS_WKVT  73728     // 384*192 bf16
#define WS_WPT   221184    // 192*192 bf16
#define WS_BQS   294912    // 192 f32 pre-scaled q-bias
#define WS_TBL   295680    // bias/mask tables (mode-dependent, log2e-scaled)

#define SWZ(row, off) ((off) ^ (((row) & 7) << 4))

__device__ __forceinline__ unsigned pk2(float a, float b) {
    bf16x2 w = { (bf16_t)a, (bf16_t)b };
    return __builtin_bit_cast(unsigned, w);
}

__global__ void prep_kernel(const float* __restrict__ Wq, const float* __restrict__ bq,
                            const float* __restrict__ Wkv, const float* __restrict__ Wproj,
                            const float* __restrict__ btab, const int* __restrict__ rel,
                            const float* __restrict__ mask,
                            bf16_t* __restrict__ wqt, bf16_t* __restrict__ wkvt,
                            bf16_t* __restrict__ wpt, float* __restrict__ bqs,
                            float* __restrict__ tbl, int mode) {
    const float SC  = 0.2550718212080052f;   // dh^-0.5 * log2e
    const float L2E = 1.4426950408889634f;
    long i = (long)blockIdx.x * 256 + threadIdx.x;
    if (i < 36864) { int n = i / 192, k = i % 192; wqt[i] = (bf16_t)(Wq[k * 192 + n] * SC); return; }
    i -= 36864;
    if (i < 73728) { int n = i / 192, k = i % 192; wkvt[i] = (bf16_t)Wkv[k * 384 + n]; return; }
    i -= 73728;
    if (i < 36864) { int n = i / 192, k = i % 192; wpt[i] = (bf16_t)Wproj[k * 192 + n]; return; }
    i -= 36864;
    if (i < 192) { bqs[i] = bq[i] * SC; return; }
    i -= 192;
    if (mode == 0) {            // presummed [64][6][49][64], log2e-scaled, pad=-1e30
        if (i < 1204224) {
            int c = i & 63; long r = i >> 6; int q = r % 49; r /= 49; int h = r % 6; int w = r / 6;
            tbl[i] = (c < 49) ? (btab[rel[q * 49 + c] * 6 + h] + mask[(size_t)w * 2401 + q * 49 + c]) * L2E
                              : -1e30f;
        }
    } else if (mode == 1) {     // bias [6][49][64] (pad 0) + mask [64][49][64] (pad -1e30)
        if (i < 18816) { int c = i & 63; int r = i >> 6; int q = r % 49; int h = r / 49;
            tbl[i] = (c < 49) ? btab[rel[q * 49 + c] * 6 + h] * L2E : 0.f; return; }
        i -= 18816;
        if (i < 200704) { int c = i & 63; long r = i >> 6; int q = r % 49; int w = r / 49;
            tbl[18816 + i] = (c < 49) ? mask[(size_t)w * 2401 + q * 49 + c] * L2E : -1e30f; }
    } else {                    // raw gathered bias [6][49][49]
        if (i < 14406) { int h = i / 2401, rc = i % 2401; tbl[i] = btab[rel[rc] * 6 + h]; }
    }
}

__global__ __launch_bounds__(512, 4) void wattn_kernel(
    const float* __restrict__ xq, const float* __restrict__ mask,
    const float* __restrict__ bkv, const float* __restrict__ bproj,
    const bf16_t* __restrict__ wqt, const bf16_t* __restrict__ wkvt, const bf16_t* __restrict__ wpt,
    const float* __restrict__ bqs, const float* __restrict__ tbl,
    float* __restrict__ out, int mode)
{
    __shared__ __align__(16) unsigned char smem[73728];
    unsigned char* QsO = smem;           // [64][384B] Q[token][chan]; O overwrites per-unit in ph3
    unsigned char* Ks  = smem + 24576;   // [64][384B] K[token][chan]
    unsigned char* Vt  = smem + 49152;   // [192][128B] V^T[chan][token]

    const int tid = threadIdx.x;
    const int wid = tid >> 6;            // 0..7
    const int lane = tid & 63;
    const int l15 = lane & 15;
    const int lg = lane >> 4;            // 0..3
    // XCD-locality swizzle (bijective bit-field swap): windows with equal (b&63)
    // cluster on one XCD -> 6*49*64 table slice (~75KB/widx * 8) stays L2-hot.
    const int t0 = blockIdx.x;
    const int b = (t0 & 0x1FC0) | ((t0 & 7) << 3) | ((t0 >> 3) & 7);
    const float* xp = xq + (size_t)b * (NTOK * CCH);
    const float LOG2E = 1.4426950408889634f;

    // ---- Phase 1+2 fused: X from global to regs, QKV projection ----
    const int mtp = wid & 1;             // token-tile pair {2*mtp, 2*mtp+1}
    const int ntq = wid >> 1;            // nt = ntq + 4k, k=0..8
    bf16x8 xf[2][6];
#pragma unroll
    for (int e = 0; e < 2; e++) {
        int tok = (mtp * 2 + e) * 16 + l15;
        const float* xrow = xp + (size_t)tok * 192;
        bool ok = (tok < NTOK);
#pragma unroll
        for (int ks = 0; ks < 6; ks++) {
            float4 a = { 0.f, 0.f, 0.f, 0.f }, c = { 0.f, 0.f, 0.f, 0.f };
            if (ok) {
                a = *(const float4*)(xrow + ks * 32 + lg * 8);
                c = *(const float4*)(xrow + ks * 32 + lg * 8 + 4);
            }
            bf16x8 f = { (bf16_t)a.x, (bf16_t)a.y, (bf16_t)a.z, (bf16_t)a.w,
                         (bf16_t)c.x, (bf16_t)c.y, (bf16_t)c.z, (bf16_t)c.w };
            xf[e][ks] = f;
        }
    }
    for (int k9 = 0; k9 < 9; k9++) {
        int nt = ntq + 4 * k9;                       // 0..35
        int kind = nt < 12 ? 0 : (nt < 24 ? 1 : 2);  // Q / K / V
        int ncol = (nt - (kind == 1 ? 12 : (kind == 2 ? 24 : 0))) * 16;
        const bf16_t* wr;
        if (kind == 0)      wr = wqt  + (size_t)(ncol + l15) * 192 + lg * 8;
        else if (kind == 1) wr = wkvt + (size_t)(ncol + l15) * 192 + lg * 8;
        else                wr = wkvt + (size_t)(192 + ncol + l15) * 192 + lg * 8;
        bf16x8 bfr[6];
#pragma unroll
        for (int ks = 0; ks < 6; ks++) bfr[ks] = *(const bf16x8*)(wr + ks * 32);

        if (kind < 2) {
            // swapped: D[outchan][token] per 16-tile; lane -> 4 consecutive outchans of one token
            float4 b4 = (kind == 0) ? *(const float4*)(bqs + ncol + lg * 4)
                                    : *(const float4*)(bkv + ncol + lg * 4);
            f32x4 acc0 = { b4.x, b4.y, b4.z, b4.w }, acc1 = acc0;
#pragma unroll
            for (int ks = 0; ks < 6; ks++) {
                acc0 = __builtin_amdgcn_mfma_f32_16x16x32_bf16(bfr[ks], xf[0][ks], acc0, 0, 0, 0);
                acc1 = __builtin_amdgcn_mfma_f32_16x16x32_bf16(bfr[ks], xf[1][ks], acc1, 0, 0, 0);
            }
            unsigned char* dst = (kind == 0) ? QsO : Ks;
            int tr0 = (mtp * 2) * 16 + l15;
            int tr1 = tr0 + 16;
            bf16x4 p0 = { (bf16_t)acc0[0], (bf16_t)acc0[1], (bf16_t)acc0[2], (bf16_t)acc0[3] };
            bf16x4 p1 = { (bf16_t)acc1[0], (bf16_t)acc1[1], (bf16_t)acc1[2], (bf16_t)acc1[3] };
            *(bf16x4*)(dst + tr0 * 384 + SWZ(tr0, ncol * 2 + lg * 8)) = p0;
            *(bf16x4*)(dst + tr1 * 384 + SWZ(tr1, ncol * 2 + lg * 8)) = p1;
        } else {
            // normal: D[token][chan]; store transposed into Vt[chan][token]
            float bv = bkv[192 + ncol + l15];
            f32x4 acc0 = { bv, bv, bv, bv }, acc1 = acc0;
#pragma unroll
            for (int ks = 0; ks < 6; ks++) {
                acc0 = __builtin_amdgcn_mfma_f32_16x16x32_bf16(xf[0][ks], bfr[ks], acc0, 0, 0, 0);
                acc1 = __builtin_amdgcn_mfma_f32_16x16x32_bf16(xf[1][ks], bfr[ks], acc1, 0, 0, 0);
            }
            int vr = ncol + l15;
            bf16x4 v0 = { (bf16_t)acc0[0], (bf16_t)acc0[1], (bf16_t)acc0[2], (bf16_t)acc0[3] };
            bf16x4 v1 = { (bf16_t)acc1[0], (bf16_t)acc1[1], (bf16_t)acc1[2], (bf16_t)acc1[3] };
            *(bf16x4*)(Vt + vr * 128 + SWZ(vr, (mtp * 2) * 32 + lg * 8)) = v0;
            *(bf16x4*)(Vt + vr * 128 + SWZ(vr, (mtp * 2 + 1) * 32 + lg * 8)) = v1;
        }
    }
    __syncthreads();

    // ---- Phase 3: attention; 24 (head,qtile) units, 3 per wave (same qt) ----
    const int widx = b & 63;
    for (int i3 = 0; i3 < 3; i3++) {
        int u = wid + 8 * i3;
        int h = u >> 2, qtl = u & 3;
        int qrow = qtl * 16 + l15;
        bf16x8 qfr = *(const bf16x8*)(QsO + qrow * 384 + SWZ(qrow, h * 64 + lg * 16));
        // QK^T (S^T orientation: col=q, row=ktok)
        f32x4 s[4];
#pragma unroll
        for (int f = 0; f < 4; f++) {
            int kr = f * 16 + l15;
            bf16x8 kfr = *(const bf16x8*)(Ks + kr * 384 + SWZ(kr, h * 64 + lg * 16));
            f32x4 z = { 0.f, 0.f, 0.f, 0.f };
            s[f] = __builtin_amdgcn_mfma_f32_16x16x32_bf16(kfr, qfr, z, 0, 0, 0);
        }
        int q = qtl * 16 + l15;
        bool qok = (q < NTOK);
        // bias + mask (log2e domain; table pads carry -1e30)
        if (mode == 0) {
#pragma unroll
            for (int f = 0; f < 4; f++) {
                if (qok) {
                    float4 bm = *(const float4*)(tbl + (((size_t)(widx * 6 + h) * 49 + q) << 6) + f * 16 + lg * 4);
                    s[f][0] += bm.x; s[f][1] += bm.y; s[f][2] += bm.z; s[f][3] += bm.w;
                }
            }
        } else if (mode == 1) {
#pragma unroll
            for (int f = 0; f < 4; f++) {
                if (qok) {
                    float4 b1 = *(const float4*)(tbl + (((size_t)(h * 49 + q)) << 6) + f * 16 + lg * 4);
                    float4 m1 = *(const float4*)(tbl + 18816 + (((size_t)(widx * 49 + q)) << 6) + f * 16 + lg * 4);
                    s[f][0] += b1.x + m1.x; s[f][1] += b1.y + m1.y;
                    s[f][2] += b1.z + m1.z; s[f][3] += b1.w + m1.w;
                }
            }
        } else {
#pragma unroll
            for (int f = 0; f < 4; f++)
#pragma unroll
                for (int j = 0; j < 4; j++) {
                    int k = f * 16 + lg * 4 + j;
                    if (k >= NTOK) s[f][j] = -1e30f;
                    else if (qok)
                        s[f][j] += (tbl[h * 2401 + q * 49 + k] + mask[(size_t)widx * 2401 + q * 49 + k]) * LOG2E;
                }
        }
        // softmax over k (exp2 domain): in-lane 16 + lg-group reduce
        float m = s[0][0];
#pragma unroll
        for (int f = 0; f < 4; f++)
#pragma unroll
            for (int j = 0; j < 4; j++) m = fmaxf(m, s[f][j]);
        m = fmaxf(m, __shfl_xor(m, 16));
        m = fmaxf(m, __shfl_xor(m, 32));
        float t = 0.f;
#pragma unroll
        for (int f = 0; f < 4; f++)
#pragma unroll
            for (int j = 0; j < 4; j++) { s[f][j] = __builtin_amdgcn_exp2f(s[f][j] - m); t += s[f][j]; }
        t += __shfl_xor(t, 16);
        t += __shfl_xor(t, 32);
        float inv = __builtin_amdgcn_rcpf(t);
        // pack P (unnormalized) and reshuffle into PV B-operand layout
        unsigned Wp[8];
#pragma unroll
        for (int f = 0; f < 4; f++) {
            Wp[f * 2 + 0] = pk2(s[f][0], s[f][1]);
            Wp[f * 2 + 1] = pk2(s[f][2], s[f][3]);
        }
        bf16x8 pa[2];
#pragma unroll
        for (int ks2 = 0; ks2 < 2; ks2++) {
            unsigned pw[4];
#pragma unroll
            for (int p = 0; p < 4; p++) {
                int src = l15 + 16 * (((lg & 1) << 1) | (p >> 1));
                unsigned v0 = (unsigned)__shfl((int)Wp[(2 * ks2) * 2 + (p & 1)], src, 64);
                unsigned v1 = (unsigned)__shfl((int)Wp[(2 * ks2 + 1) * 2 + (p & 1)], src, 64);
                pw[p] = (lg & 2) ? v1 : v0;
            }
            uint4 pp = { pw[0], pw[1], pw[2], pw[3] };
            pa[ks2] = __builtin_bit_cast(bf16x8, pp);
        }
        // PV (swapped): D[chan][q]; normalize post-hoc with inv (per-lane q=l15)
#pragma unroll
        for (int dt = 0; dt < 2; dt++) {
            f32x4 acc = { 0.f, 0.f, 0.f, 0.f };
#pragma unroll
            for (int ks2 = 0; ks2 < 2; ks2++) {
                int vr = h * 32 + dt * 16 + l15;
                bf16x8 vfr = *(const bf16x8*)(Vt + vr * 128 + SWZ(vr, ks2 * 64 + lg * 16));
                acc = __builtin_amdgcn_mfma_f32_16x16x32_bf16(vfr, pa[ks2], acc, 0, 0, 0);
            }
            int orow = qtl * 16 + l15;
            bf16x4 op4 = { (bf16_t)(acc[0] * inv), (bf16_t)(acc[1] * inv),
                           (bf16_t)(acc[2] * inv), (bf16_t)(acc[3] * inv) };
            // overwrites this unit's own Q region (disjoint across units) -> no barrier needed
            *(bf16x4*)(QsO + orow * 384 + SWZ(orow, h * 64 + dt * 32 + lg * 8)) = op4;
        }
    }
    __syncthreads();

    // ---- Phase 4: out projection (swapped), float4 global stores; 6 units/wave ----
    {
        float* op = out + (size_t)b * (NTOK * CCH);
        bf16x8 bfr[6];
        float4 b4 = { 0.f, 0.f, 0.f, 0.f };
        int prev_nt = -1;
        for (int i = 0; i < 6; i++) {
            int u = wid * 6 + i;
            int nt = u >> 2, mt = u & 3;
            if (nt != prev_nt) {
                prev_nt = nt;
                const bf16_t* wr = wpt + (size_t)(nt * 16 + l15) * 192 + lg * 8;
#pragma unroll
                for (int ks = 0; ks < 6; ks++) bfr[ks] = *(const bf16x8*)(wr + ks * 32);
                b4 = *(const float4*)(bproj + nt * 16 + lg * 4);
            }
            int orow = mt * 16 + l15;
            f32x4 acc = { b4.x, b4.y, b4.z, b4.w };
#pragma unroll
            for (int ks = 0; ks < 6; ks++) {
                bf16x8 of = *(const bf16x8*)(QsO + orow * 384 + SWZ(orow, ks * 64 + lg * 16));
                acc = __builtin_amdgcn_mfma_f32_16x16x32_bf16(bfr[ks], of, acc, 0, 0, 0);
            }
            if (orow < NTOK) {
                float4 st = { acc[0], acc[1], acc[2], acc[3] };
                *(float4*)(op + orow * 192 + nt * 16 + lg * 4) = st;
            }
        }
    }
}

extern "C" void kernel_launch(void* const* d_in, const int* in_sizes, int n_in,
                              void* d_out, int out_size, void* d_ws, size_t ws_size,
                              hipStream_t stream) {
    const float* xq    = (const float*)d_in[0];
    const float* mask  = (const float*)d_in[1];
    const float* Wq    = (const float*)d_in[2];
    const float* bq    = (const float*)d_in[3];
    const float* Wkv   = (const float*)d_in[4];
    const float* bkv   = (const float*)d_in[5];
    const float* Wproj = (const float*)d_in[6];
    const float* bproj = (const float*)d_in[7];
    const float* btab  = (const float*)d_in[8];
    const int*   rel   = (const int*)d_in[9];
    float* out = (float*)d_out;

    char* ws = (char*)d_ws;
    bf16_t* wqt  = (bf16_t*)(ws + WS_WQT);
    bf16_t* wkvt = (bf16_t*)(ws + WS_WKVT);
    bf16_t* wpt  = (bf16_t*)(ws + WS_WPT);
    float*  bqs  = (float*)(ws + WS_BQS);
    float*  tbl  = (float*)(ws + WS_TBL);

    size_t need0 = (size_t)WS_TBL + 1204224u * 4u;   // presummed padded table
    size_t need1 = (size_t)WS_TBL + 219520u * 4u;    // split padded tables
    int mode = (ws_size >= need0) ? 0 : (ws_size >= need1 ? 1 : 2);

    long tblN = (mode == 0) ? 1204224L : (mode == 1 ? 219520L : 14406L);
    long prep_elems = 147648L + tblN;
    int prep_blocks = (int)((prep_elems + 255) / 256);
    prep_kernel<<<prep_blocks, 256, 0, stream>>>(Wq, bq, Wkv, Wproj, btab, rel, mask,
                                                 wqt, wkvt, wpt, bqs, tbl, mode);
    wattn_kernel<<<8192, 512, 0, stream>>>(xq, mask, bkv, bproj, wqt, wkvt, wpt,
                                           bqs, tbl, out, mode);
}